// Round 16
// baseline (35.151 us; speedup 1.0000x reference)
//
#include <hip/hip_runtime.h>

// HOG layer: (32,1,512,512) f32 -> (32,10,64,64) f32
// CORRECTNESS-PINNED decisions (R12/R14/R15 pass, absmax 0.0371):
//   f32 seq conv (row-major sequential taps) -> fast bin via 9 cross-product
//   sign tests in folded [0,pi) -> pixels within 4e-6*mag of any boundary are
//   flagged and take the VERBATIM R12 slow path (OCML atan2f -> w10 =
//   fl32(phs*C10) -> floor -> mod 10 -> boundary 50/50 split, mag<4.6 gate)
//   -> 8x8 mean pool.
// R16 (scheduling only): slow path deferred OUT of the hot j-loop (1 branch
// per 8-pixel strip instead of 16); cheaper fold (ax=|gx|, ay=gy^sign(gx) --
// differs from R15 only at gx==0 which is always flagged); k=5 cross is -ay
// (mul/fma elided). Deposit values identical; only intra-cell summation order
// changes for flagged pixels (error ~1ulp of acc, << 0.0045 margin).

namespace {
constexpr int H = 512, W = 512, NB = 10;
}

__global__ __launch_bounds__(256) void hog_kernel(const float* __restrict__ xin,
                                                  float* __restrict__ out) {
    const int tid  = threadIdx.x;
    const int wid  = (blockIdx.x * blockDim.x + tid) >> 6;
    const int lane = tid & 63;

    const int n    = wid >> 9;        // image
    const int rem  = wid & 511;
    const int ph   = rem >> 3;        // pooled row 0..63
    const int pwg  = rem & 7;         // group of 8 pooled cols
    const int cell = lane >> 3;       // pooled col within group
    const int r    = lane & 7;        // pixel row within cell

    const int pw = pwg * 8 + cell;
    const int y  = ph * 8 + r;
    const int x0 = pw * 8;

    const float* img = xin + (size_t)n * H * W;

    // pinned: C10 = fl32( fl32(1/pi32) * 10 )
    const float PI32 = 3.14159274101257324f;            // 0x40490fdb
    const float C10  = __fmul_rn(__fdiv_rn(1.0f, PI32), 10.0f);

    // f32 boundary normals: cos(k*pi/10), sin(k*pi/10), k=1..9 (index k-1)
    const float CB[9] = { 0.95105651629f,  0.80901699437f,  0.58778525229f,
                          0.30901699437f,  0.0f,           -0.30901699437f,
                         -0.58778525229f, -0.80901699437f, -0.95105651629f };
    const float SB[9] = { 0.30901699437f,  0.58778525229f,  0.80901699437f,
                          0.95105651629f,  1.0f,            0.95105651629f,
                          0.80901699437f,  0.58778525229f,  0.30901699437f };

    // ---- one-shot strip preload: rows y-1..y+1, cols x0-1..x0+8 ----
    float row[3][10];
#pragma unroll
    for (int dy = 0; dy < 3; ++dy) {
        const int ry = y - 1 + dy;
        if (ry >= 0 && ry < H) {
            const float* p = img + (size_t)ry * W + x0;
            row[dy][0] = (x0 > 0) ? p[-1] : 0.0f;
            const float4 a = *reinterpret_cast<const float4*>(p);      // 32B-aligned
            const float4 b = *reinterpret_cast<const float4*>(p + 4);
            row[dy][1] = a.x; row[dy][2] = a.y; row[dy][3] = a.z; row[dy][4] = a.w;
            row[dy][5] = b.x; row[dy][6] = b.y; row[dy][7] = b.z; row[dy][8] = b.w;
            row[dy][9] = (x0 + 8 < W) ? p[8] : 0.0f;
        } else {
#pragma unroll
            for (int i = 0; i < 10; ++i) row[dy][i] = 0.0f;
        }
    }

    float acc[NB];
#pragma unroll
    for (int b = 0; b < NB; ++b) acc[b] = 0.0f;

    int flags = 0;

    // ================= hot loop: branch-free fast path =================
#pragma unroll
    for (int j = 0; j < 8; ++j) {
        const float t0 = row[0][j], t1 = row[0][j + 1], t2 = row[0][j + 2];
        const float m0 = row[1][j],                      m2 = row[1][j + 2];
        const float b0 = row[2][j], b1 = row[2][j + 1], b2 = row[2][j + 2];

        // pinned: f32 conv, sequential row-major taps
        const float gx = ((((t0 - t2) + 2.0f * m0) - 2.0f * m2) + b0) - b2;
        const float gy = ((((t0 + 2.0f * t1) + t2) - b0) - 2.0f * b1) - b2;

        const float mag = sqrtf(gx * gx + gy * gy);

        // fold to [0,pi): ax = |gx|; ay = gy with gx's sign xored in.
        // (gx==0 handled by slow path: such pixels are always flagged)
        const float ax = fabsf(gx);
        const float ay = __uint_as_float(__float_as_uint(gy) ^
                                         (__float_as_uint(gx) & 0x80000000u));

        int   binf = 0;
        float minc = ax;                      // |ax|: the 0/pi wrap boundary
#pragma unroll
        for (int k = 0; k < 9; ++k) {
            if (k == 4) continue;             // boundary pi/2: c = -ay exactly
            const float c = ax * CB[k] - ay * SB[k];
            binf += (c >= 0.0f) ? 1 : 0;
            minc = fminf(minc, fabsf(c));
        }
        binf += (-ay >= 0.0f) ? 1 : 0;        // k=4 test (value-identical)
        minc = fminf(minc, fabsf(ay));

        const bool flagged = (minc < 4e-6f * mag);
        flags |= flagged ? (1 << j) : 0;
        const float dep = flagged ? 0.0f : mag;

#pragma unroll
        for (int b = 0; b < NB; ++b) acc[b] += (binf == b) ? dep : 0.0f;
    }

    // ============ cold path: verbatim R12 pipeline, execz-skipped ============
    if (flags) {
#pragma unroll
        for (int j = 0; j < 8; ++j) {
            if (flags & (1 << j)) {
                const float t0 = row[0][j], t1 = row[0][j + 1], t2 = row[0][j + 2];
                const float m0 = row[1][j],                      m2 = row[1][j + 2];
                const float b0 = row[2][j], b1 = row[2][j + 1], b2 = row[2][j + 2];
                const float gx = ((((t0 - t2) + 2.0f * m0) - 2.0f * m2) + b0) - b2;
                const float gy = ((((t0 + 2.0f * t1) + t2) - b0) - 2.0f * b1) - b2;
                const float mag = sqrtf(gx * gx + gy * gy);

                const float phs = atan2f(gx, gy);          // OCML -- pinned
                const float w10 = __fmul_rn(phs, C10);
                int bi = (int)floorf(w10);
                bi %= 10;
                if (bi < 0) bi += 10;

                float half = 0.0f;
                int   balt = 0;
                const float rk  = rintf(w10);
                const float eps = fmaxf(4.0f * fabsf(w10) * 1.1920929e-7f, 1.5e-6f);
                if (fabsf(w10 - rk) < eps && mag < 4.6f) {
                    const int k  = (int)rk;
                    int kb = k % 10;       if (kb < 0) kb += 10;
                    int ka = (k - 1) % 10; if (ka < 0) ka += 10;
                    balt = (bi == kb) ? ka : kb;
                    half = 0.5f * mag;
                }

                const float dep = mag - half;
#pragma unroll
                for (int b = 0; b < NB; ++b) acc[b] += (bi == b) ? dep : 0.0f;
                if (half > 0.0f) {
#pragma unroll
                    for (int b = 0; b < NB; ++b) acc[b] += (balt == b) ? half : 0.0f;
                }
            }
        }
    }

    // reduce the 8 row-lanes of each cell
    float w1 = 0.0f, w2 = 0.0f;
#pragma unroll
    for (int b = 0; b < NB; ++b) {
        float v = acc[b];
        v += __shfl_xor(v, 1, 64);
        v += __shfl_xor(v, 2, 64);
        v += __shfl_xor(v, 4, 64);
        if (b < 8) { w1 = (r == b)     ? v : w1; }
        else       { w2 = (r == b - 8) ? v : w2; }
    }

    const float inv = 1.0f / 64.0f;
    const size_t obase = (((size_t)n * NB) * 64 + (size_t)ph) * 64 + (size_t)pw;
    out[obase + (size_t)r * 4096] = w1 * inv;
    if (r < 2) out[obase + (size_t)(8 + r) * 4096] = w2 * inv;
}

extern "C" void kernel_launch(void* const* d_in, const int* in_sizes, int n_in,
                              void* d_out, int out_size, void* d_ws, size_t ws_size,
                              hipStream_t stream) {
    const float* x = (const float*)d_in[0];
    float* out = (float*)d_out;
    hipLaunchKernelGGL(hog_kernel, dim3(4096), dim3(256), 0, stream, x, out);
}

// Round 17
// 27.782 us; speedup vs baseline: 1.2652x; 1.2652x over previous
//
#include <hip/hip_runtime.h>

// HOG layer: (32,1,512,512) f32 -> (32,10,64,64) f32
// CORRECTNESS-PINNED decisions (R12 pass, absmax 0.0371):
//   f32 seq conv (row-major sequential taps) -> bin = floor(fl32(atan2f*C10))
//   mod 10 with boundary-ambiguity 50/50 split (eps window, mag<4.6 gate)
//   -> 8x8 mean pool.
// R17 fast path: w10 approximated directly via octant-reduced Hastings deg-9
// atan polynomial in w10 units (|err| <= 3.6e-5 incl. f32 rounding; OCML
// pipeline err <= 2.6e-6). Pixels with |w10a - rint(w10a)| < 1.25e-4 are
// flagged -> VERBATIM R12 slow path inline (R15 structure; R16's deferral
// regressed). Unflagged: floor provably == R12's bin, no mod needed, deposit
// mag. Flagged superset of R12's split window (4.8e-6). Bit-identical output.

namespace {
constexpr int H = 512, W = 512, NB = 10;
}

__global__ __launch_bounds__(256) void hog_kernel(const float* __restrict__ xin,
                                                  float* __restrict__ out) {
    const int tid  = threadIdx.x;
    const int wid  = (blockIdx.x * blockDim.x + tid) >> 6;
    const int lane = tid & 63;

    const int n    = wid >> 9;        // image
    const int rem  = wid & 511;
    const int ph   = rem >> 3;        // pooled row 0..63
    const int pwg  = rem & 7;         // group of 8 pooled cols
    const int cell = lane >> 3;       // pooled col within group
    const int r    = lane & 7;        // pixel row within cell

    const int pw = pwg * 8 + cell;
    const int y  = ph * 8 + r;
    const int x0 = pw * 8;

    const float* img = xin + (size_t)n * H * W;

    // pinned: C10 = fl32( fl32(1/pi32) * 10 )
    const float PI32 = 3.14159274101257324f;            // 0x40490fdb
    const float C10  = __fmul_rn(__fdiv_rn(1.0f, PI32), 10.0f);

    // Hastings (A&S 4.4.47) atan coeffs scaled by 10/pi (w10 units)
    const float P0 =  3.1826723f;   // 0.9998660 * 3.1830989
    const float P1 = -1.0513758f;   // -0.3302995 * "
    const float P2 =  0.5734066f;   //  0.1801410 * "
    const float P3 = -0.2709868f;   // -0.0851330 * "
    const float P4 =  0.0663202f;   //  0.0208351 * "
    const float EPSW = 1.25e-4f;

    // ---- one-shot strip preload: rows y-1..y+1, cols x0-1..x0+8 ----
    float row[3][10];
#pragma unroll
    for (int dy = 0; dy < 3; ++dy) {
        const int ry = y - 1 + dy;
        if (ry >= 0 && ry < H) {
            const float* p = img + (size_t)ry * W + x0;
            row[dy][0] = (x0 > 0) ? p[-1] : 0.0f;
            const float4 a = *reinterpret_cast<const float4*>(p);      // 32B-aligned
            const float4 b = *reinterpret_cast<const float4*>(p + 4);
            row[dy][1] = a.x; row[dy][2] = a.y; row[dy][3] = a.z; row[dy][4] = a.w;
            row[dy][5] = b.x; row[dy][6] = b.y; row[dy][7] = b.z; row[dy][8] = b.w;
            row[dy][9] = (x0 + 8 < W) ? p[8] : 0.0f;
        } else {
#pragma unroll
            for (int i = 0; i < 10; ++i) row[dy][i] = 0.0f;
        }
    }

    float acc[NB];
#pragma unroll
    for (int b = 0; b < NB; ++b) acc[b] = 0.0f;

#pragma unroll
    for (int j = 0; j < 8; ++j) {
        const float t0 = row[0][j], t1 = row[0][j + 1], t2 = row[0][j + 2];
        const float m0 = row[1][j],                      m2 = row[1][j + 2];
        const float b0 = row[2][j], b1 = row[2][j + 1], b2 = row[2][j + 2];

        // pinned: f32 conv, sequential row-major taps
        const float gx = ((((t0 - t2) + 2.0f * m0) - 2.0f * m2) + b0) - b2;
        const float gy = ((((t0 + 2.0f * t1) + t2) - b0) - 2.0f * b1) - b2;

        const float mag = sqrtf(gx * gx + gy * gy);

        // fold to [0,pi): ax = |gx|, ay = gy ^ sign(gx).
        // (gx==0: either flagged (w near 0/5/10) or mag==0 -> harmless)
        const float ax = fabsf(gx);
        const float ay = __uint_as_float(__float_as_uint(gy) ^
                                         (__float_as_uint(gx) & 0x80000000u));
        const float aay = fabsf(ay);

        // octant-reduced w10 approximation:
        //   q: ax>aay -> theta = pi/2 - atan(ay/ax)   -> w = 5 - s
        //  !q:          theta = atan(ax/aay) (ay>0) or pi - atan(ax/aay)
        const bool  q   = ax > aay;
        const float den = q ? ax : aay;
        const float num = q ? ay : ax;
        const float t   = num * __frcp_rn(den);        // v_rcp_f32, ~1ulp
        const float u   = t * t;
        float p = fmaf(P4, u, P3);
        p = fmaf(p, u, P2);
        p = fmaf(p, u, P1);
        p = fmaf(p, u, P0);
        const float s = t * p;                          // atan in w10 units
        const float w = q ? (5.0f - s) : ((ay > 0.0f) ? s : (10.0f - s));

        const float dist = fabsf(w - rintf(w));
        const bool flagged = !(dist >= EPSW);           // catches NaN w too? no:
        // NaN w (only when mag==0) -> dist NaN -> !(NaN>=eps)=true -> slow path
        // with atan2f(0,0)=0 -> bin 0, dep 0. Harmless and well-defined.

        int   bi;
        float half = 0.0f;
        int   balt = 0;
        if (!flagged) {
            bi = (int)floorf(w);                        // provably in [0,9]
        } else {
            // ---- R12 slow path, verbatim ----
            const float phs = atan2f(gx, gy);           // OCML -- pinned
            const float w10 = __fmul_rn(phs, C10);
            bi = (int)floorf(w10);
            bi %= 10;
            if (bi < 0) bi += 10;
            const float rk  = rintf(w10);
            const float eps = fmaxf(4.0f * fabsf(w10) * 1.1920929e-7f, 1.5e-6f);
            if (fabsf(w10 - rk) < eps && mag < 4.6f) {
                const int k  = (int)rk;
                int kb = k % 10;       if (kb < 0) kb += 10;
                int ka = (k - 1) % 10; if (ka < 0) ka += 10;
                balt = (bi == kb) ? ka : kb;
                half = 0.5f * mag;
            }
        }

        const float dep = mag - half;
#pragma unroll
        for (int b = 0; b < NB; ++b) acc[b] += (bi == b) ? dep : 0.0f;
        if (half > 0.0f) {                              // rare: execz-skipped
#pragma unroll
            for (int b = 0; b < NB; ++b) acc[b] += (balt == b) ? half : 0.0f;
        }
    }

    // reduce the 8 row-lanes of each cell
    float w1 = 0.0f, w2 = 0.0f;
#pragma unroll
    for (int b = 0; b < NB; ++b) {
        float v = acc[b];
        v += __shfl_xor(v, 1, 64);
        v += __shfl_xor(v, 2, 64);
        v += __shfl_xor(v, 4, 64);
        if (b < 8) { w1 = (r == b)     ? v : w1; }
        else       { w2 = (r == b - 8) ? v : w2; }
    }

    const float inv = 1.0f / 64.0f;
    const size_t obase = (((size_t)n * NB) * 64 + (size_t)ph) * 64 + (size_t)pw;
    out[obase + (size_t)r * 4096] = w1 * inv;
    if (r < 2) out[obase + (size_t)(8 + r) * 4096] = w2 * inv;
}

extern "C" void kernel_launch(void* const* d_in, const int* in_sizes, int n_in,
                              void* d_out, int out_size, void* d_ws, size_t ws_size,
                              hipStream_t stream) {
    const float* x = (const float*)d_in[0];
    float* out = (float*)d_out;
    hipLaunchKernelGGL(hog_kernel, dim3(4096), dim3(256), 0, stream, x, out);
}

// Round 18
// 27.416 us; speedup vs baseline: 1.2821x; 1.0134x over previous
//
#include <hip/hip_runtime.h>

// HOG layer: (32,1,512,512) f32 -> (32,10,64,64) f32
// CORRECTNESS-PINNED decisions (R12 pass, absmax 0.0371):
//   f32 seq conv (row-major sequential taps) -> bin = floor(fl32(atan2f*C10))
//   mod 10 with boundary-ambiguity 50/50 split (eps window, mag<4.6 gate)
//   -> 8x8 mean pool.
// Fast path (R17, verified bit-identical): octant-reduced Hastings deg-9 atan
// in w10 units; |w - rint(w)| < 1.25e-4 -> flagged -> VERBATIM R12 slow path.
// R18 (packed fp32, bit-identical): pixel PAIRS via float2 -> v_pk_add/mul/fma
// for conv / mag^2 / polynomial; packed 5xfloat2 accumulator with fma-gated
// scatter (gate 1.0/0.0 -> bit-identical to conditional add; +0 adds are
// exact identities). Scalar: sqrt, rcp, compares, selects, slow path.

namespace {
constexpr int H = 512, W = 512, NB = 10;
}

typedef __attribute__((ext_vector_type(2))) float f32x2;

__device__ __forceinline__ f32x2 vfma2(f32x2 a, f32x2 b, f32x2 c) {
#if __has_builtin(__builtin_elementwise_fma)
    return __builtin_elementwise_fma(a, b, c);
#else
    f32x2 r; r.x = fmaf(a.x, b.x, c.x); r.y = fmaf(a.y, b.y, c.y); return r;
#endif
}

__global__ __launch_bounds__(256) void hog_kernel(const float* __restrict__ xin,
                                                  float* __restrict__ out) {
    const int tid  = threadIdx.x;
    const int wid  = (blockIdx.x * blockDim.x + tid) >> 6;
    const int lane = tid & 63;

    const int n    = wid >> 9;        // image
    const int rem  = wid & 511;
    const int ph   = rem >> 3;        // pooled row 0..63
    const int pwg  = rem & 7;         // group of 8 pooled cols
    const int cell = lane >> 3;       // pooled col within group
    const int r    = lane & 7;        // pixel row within cell

    const int pw = pwg * 8 + cell;
    const int y  = ph * 8 + r;
    const int x0 = pw * 8;

    const float* img = xin + (size_t)n * H * W;

    // pinned: C10 = fl32( fl32(1/pi32) * 10 )
    const float PI32 = 3.14159274101257324f;            // 0x40490fdb
    const float C10  = __fmul_rn(__fdiv_rn(1.0f, PI32), 10.0f);

    // Hastings (A&S 4.4.47) atan coeffs scaled by 10/pi (w10 units) -- pinned
    const f32x2 P0v = { 3.1826723f,  3.1826723f};
    const f32x2 P1v = {-1.0513758f, -1.0513758f};
    const f32x2 P2v = { 0.5734066f,  0.5734066f};
    const f32x2 P3v = {-0.2709868f, -0.2709868f};
    const f32x2 P4v = { 0.0663202f,  0.0663202f};
    const float EPSW = 1.25e-4f;

    // ---- one-shot strip preload: rows y-1..y+1, cols x0-1..x0+8 ----
    float row[3][10];
#pragma unroll
    for (int dy = 0; dy < 3; ++dy) {
        const int ry = y - 1 + dy;
        if (ry >= 0 && ry < H) {
            const float* p = img + (size_t)ry * W + x0;
            row[dy][0] = (x0 > 0) ? p[-1] : 0.0f;
            const float4 a = *reinterpret_cast<const float4*>(p);      // 32B-aligned
            const float4 b = *reinterpret_cast<const float4*>(p + 4);
            row[dy][1] = a.x; row[dy][2] = a.y; row[dy][3] = a.z; row[dy][4] = a.w;
            row[dy][5] = b.x; row[dy][6] = b.y; row[dy][7] = b.z; row[dy][8] = b.w;
            row[dy][9] = (x0 + 8 < W) ? p[8] : 0.0f;
        } else {
#pragma unroll
            for (int i = 0; i < 10; ++i) row[dy][i] = 0.0f;
        }
    }

    f32x2 acc2[5];
#pragma unroll
    for (int p = 0; p < 5; ++p) acc2[p] = (f32x2){0.0f, 0.0f};

    // per-pixel tail: w-selection, flag, (rare) slow path, packed scatter
    auto process = [&](float gx, float gy, float mag, bool q, float ay, float s) {
        const float w = q ? (5.0f - s) : ((ay > 0.0f) ? s : (10.0f - s));
        const float dist = fabsf(w - rintf(w));
        const bool flagged = !(dist >= EPSW);   // NaN-safe: NaN -> flagged

        int   bi;
        float half = 0.0f;
        int   balt = 0;
        if (!flagged) {
            bi = (int)w;                        // w in (EPSW, 10-EPSW): trunc==floor
        } else {
            // ---- R12 slow path, verbatim ----
            const float phs = atan2f(gx, gy);   // OCML -- pinned
            const float w10 = __fmul_rn(phs, C10);
            bi = (int)floorf(w10);
            bi %= 10;
            if (bi < 0) bi += 10;
            const float rk  = rintf(w10);
            const float eps = fmaxf(4.0f * fabsf(w10) * 1.1920929e-7f, 1.5e-6f);
            if (fabsf(w10 - rk) < eps && mag < 4.6f) {
                const int k  = (int)rk;
                int kb = k % 10;       if (kb < 0) kb += 10;
                int ka = (k - 1) % 10; if (ka < 0) ka += 10;
                balt = (bi == kb) ? ka : kb;
                half = 0.5f * mag;
            }
        }

        const float dep = mag - half;
        const int   h   = bi >> 1;
        const f32x2 P   = (bi & 1) ? (f32x2){0.0f, dep} : (f32x2){dep, 0.0f};
#pragma unroll
        for (int p = 0; p < 5; ++p) {
            const float g = (h == p) ? 1.0f : 0.0f;
            acc2[p] = vfma2(P, (f32x2){g, g}, acc2[p]);
        }
        if (half > 0.0f) {                      // rare: execz-skipped
            const int   h2 = balt >> 1;
            const f32x2 Q  = (balt & 1) ? (f32x2){0.0f, half} : (f32x2){half, 0.0f};
#pragma unroll
            for (int p = 0; p < 5; ++p) {
                const float g = (h2 == p) ? 1.0f : 0.0f;
                acc2[p] = vfma2(Q, (f32x2){g, g}, acc2[p]);
            }
        }
    };

#pragma unroll
    for (int j = 0; j < 8; j += 2) {
        // packed operands for pixels j (lo) and j+1 (hi)
        const f32x2 t0v = {row[0][j],     row[0][j + 1]};
        const f32x2 t1v = {row[0][j + 1], row[0][j + 2]};
        const f32x2 t2v = {row[0][j + 2], row[0][j + 3]};
        const f32x2 m0v = {row[1][j],     row[1][j + 1]};
        const f32x2 m2v = {row[1][j + 2], row[1][j + 3]};
        const f32x2 b0v = {row[2][j],     row[2][j + 1]};
        const f32x2 b1v = {row[2][j + 1], row[2][j + 2]};
        const f32x2 b2v = {row[2][j + 2], row[2][j + 3]};

        // pinned conv (per-half op order == scalar sequential row-major)
        const f32x2 gxv = ((((t0v - t2v) + 2.0f * m0v) - 2.0f * m2v) + b0v) - b2v;
        const f32x2 gyv = ((((t0v + 2.0f * t1v) + t2v) - b0v) - 2.0f * b1v) - b2v;

        const f32x2 msq = gxv * gxv + gyv * gyv;
        const float mag0 = sqrtf(msq.x), mag1 = sqrtf(msq.y);

        // fold to [0,pi): ax=|gx|, ay = gy ^ sign(gx)  (gx==0 -> flagged)
        const float gx0 = gxv.x, gy0 = gyv.x, gx1 = gxv.y, gy1 = gyv.y;
        const float ax0 = fabsf(gx0), ax1 = fabsf(gx1);
        const float ay0 = __uint_as_float(__float_as_uint(gy0) ^
                                          (__float_as_uint(gx0) & 0x80000000u));
        const float ay1 = __uint_as_float(__float_as_uint(gy1) ^
                                          (__float_as_uint(gx1) & 0x80000000u));
        const float aay0 = fabsf(ay0), aay1 = fabsf(ay1);

        const bool q0 = ax0 > aay0, q1 = ax1 > aay1;
        const float den0 = q0 ? ax0 : aay0, den1 = q1 ? ax1 : aay1;
        const float num0 = q0 ? ay0 : ax0,  num1 = q1 ? ay1 : ax1;

        const f32x2 rv   = {__frcp_rn(den0), __frcp_rn(den1)};
        const f32x2 numv = {num0, num1};
        const f32x2 tv   = numv * rv;
        const f32x2 uv   = tv * tv;
        f32x2 pv = vfma2(P4v, uv, P3v);
        pv = vfma2(pv, uv, P2v);
        pv = vfma2(pv, uv, P1v);
        pv = vfma2(pv, uv, P0v);
        const f32x2 sv = tv * pv;               // atan in w10 units

        process(gx0, gy0, mag0, q0, ay0, sv.x);
        process(gx1, gy1, mag1, q1, ay1, sv.y);
    }

    // unpack + reduce the 8 row-lanes of each cell
    float acc[NB];
#pragma unroll
    for (int p = 0; p < 5; ++p) { acc[2 * p] = acc2[p].x; acc[2 * p + 1] = acc2[p].y; }

    float w1 = 0.0f, w2 = 0.0f;
#pragma unroll
    for (int b = 0; b < NB; ++b) {
        float v = acc[b];
        v += __shfl_xor(v, 1, 64);
        v += __shfl_xor(v, 2, 64);
        v += __shfl_xor(v, 4, 64);
        if (b < 8) { w1 = (r == b)     ? v : w1; }
        else       { w2 = (r == b - 8) ? v : w2; }
    }

    const float inv = 1.0f / 64.0f;
    const size_t obase = (((size_t)n * NB) * 64 + (size_t)ph) * 64 + (size_t)pw;
    out[obase + (size_t)r * 4096] = w1 * inv;
    if (r < 2) out[obase + (size_t)(8 + r) * 4096] = w2 * inv;
}

extern "C" void kernel_launch(void* const* d_in, const int* in_sizes, int n_in,
                              void* d_out, int out_size, void* d_ws, size_t ws_size,
                              hipStream_t stream) {
    const float* x = (const float*)d_in[0];
    float* out = (float*)d_out;
    hipLaunchKernelGGL(hog_kernel, dim3(4096), dim3(256), 0, stream, x, out);
}